// Round 9
// baseline (61828.436 us; speedup 1.0000x reference)
//
#include <hip/hip_runtime.h>
#include <stdint.h>

#define S_ 128
#define L_ 128
#define E_ 300
#define H_ 300
#define NMAX (S_*L_)          // 16384
#define R_ 1200               // 4*H
#define D_ 600
#define XW_STRIDE ((size_t)NMAX*R_)

// ---------------- prep: prefix sums, token->(s,l) map, zero h buffers -------
__global__ void prep_kernel(const int* __restrict__ lengths, int* __restrict__ meta,
                            int* __restrict__ map, unsigned long long* __restrict__ hbuf) {
    __shared__ int offs[S_];
    int tid = threadIdx.x;
    if (tid == 0) {
        int acc = 0;
        for (int s = 0; s < S_; s++) { offs[s] = acc; acc += lengths[s]; }
        meta[0] = acc;   // N total
    }
    __syncthreads();
    for (int s = tid; s < S_; s += blockDim.x) {
        int o = offs[s], len = lengths[s];
        for (int l = 0; l < len; l++) map[o + l] = s * L_ + l;
    }
    // zero hbuf: [2 dirs][2 slots][320] u64 (tag 0 == valid h_0 = 0)
    for (int i = tid; i < 2*2*320; i += blockDim.x) hbuf[i] = 0ull;
}

// ---------------- xw = embeds @ Wih^T + (bih+bhh), both directions ----------
// Quarter-split: unit u = by*256+tid; r = u>>2 (output row 0..2559), q = u&3.
// Each thread holds only 19 float4 weights (no-spill footprint), combines
// quarter partials via shfl_xor(1,2); q==0 stores.
__global__ __launch_bounds__(256, 1) void xw_kernel(
    const int* __restrict__ tokens, const float* __restrict__ table,
    const float* __restrict__ Wih_f, const float* __restrict__ bih_f, const float* __restrict__ bhh_f,
    const float* __restrict__ Wih_b, const float* __restrict__ bih_b, const float* __restrict__ bhh_b,
    const int* __restrict__ meta, const int* __restrict__ map, float* __restrict__ xw) {
    const int N = meta[0];
    const int n0 = blockIdx.x * 32;
    if (n0 >= N) return;
    const int u = blockIdx.y * 256 + threadIdx.x;   // 0..10239
    const int r = u >> 2;                           // output row 0..2559
    const int q = u & 3;                            // column quarter
    const bool vr = (r < 2*R_);
    const int dir = (r >= R_) ? 1 : 0;
    const int rr = vr ? (r - dir * R_) : 0;
    const float* W = dir ? Wih_b : Wih_f;
    float bias = 0.f;
    float4 w4[19];
    {
        const float* wr = W + (size_t)rr * E_ + q * 76;
        #pragma unroll
        for (int j = 0; j < 18; j++) w4[j] = vr ? *(const float4*)(wr + 4*j)
                                                : make_float4(0.f,0.f,0.f,0.f);
        w4[18] = (vr && q < 3) ? *(const float4*)(wr + 72) : make_float4(0.f,0.f,0.f,0.f);
        if (vr && q == 0) bias = dir ? (bih_b[rr] + bhh_b[rr]) : (bih_f[rr] + bhh_f[rr]);
    }
    float* xwd = xw + (size_t)dir * XW_STRIDE;
    const int iend = min(32, N - n0);
    for (int i = 0; i < iend; i++) {
        const int n = n0 + i;
        const int tok = tokens[map[n]];                  // uniform
        const float* arow = table + (size_t)tok * E_ + q * 76;
        float a0 = bias, a1 = 0.f, a2 = 0.f, a3 = 0.f;
        #pragma unroll
        for (int j = 0; j < 19; j++) {
            float4 a4 = *(const float4*)(arow + 4*j);    // 4 addrs/wave
            a0 = fmaf(w4[j].x, a4.x, a0);
            a1 = fmaf(w4[j].y, a4.y, a1);
            a2 = fmaf(w4[j].z, a4.z, a2);
            a3 = fmaf(w4[j].w, a4.w, a3);
        }
        float sum = (a0 + a1) + (a2 + a3);
        sum += __shfl_xor(sum, 1);
        sum += __shfl_xor(sum, 2);
        if (vr && q == 0) xwd[(size_t)n * R_ + rr] = sum;
    }
}
// note: q==3 reads arow cols 228..303; table rows are 300 long, so cols
// 300..303 read into the NEXT row's data -- but w4[18] is zero there, so the
// products vanish. Last table row: guarded because w4[18]=0 for q==3 always.

// ---------------- sequential BiLSTM scan -------------------------------------
__device__ __forceinline__ float sel4(int m, float a, float b, float c, float d) {
    float r = a;
    r = (m == 1) ? b : r;
    r = (m == 2) ? c : r;
    r = (m == 3) ? d : r;
    return r;
}
// fast activations (v_exp_f32 + v_rcp_f32); NaN-free at +/-inf
__device__ __forceinline__ float sigm(float x) {
    return __builtin_amdgcn_rcpf(1.f + __expf(-x));
}
__device__ __forceinline__ float tanh_fast(float x) {
    return 1.f - 2.f * __builtin_amdgcn_rcpf(1.f + __expf(2.f * x));
}

#define WSTRIDE 305   // 305 % 32 = 17 (odd) -> rows spread across all banks

// grid: 20 blocks x 512 threads. block b: dir=b/10, blk=b%10 (30 h-dims).
// lane: q=lane&3 (col quarter), gate=(lane>>2)&3, dloc=lane>>4; wave w:
// local dim ld = w*4+dloc (0..29; wave7 dloc>=2 invalid, clamped).
// Weights in LDS [120][305] f32 (padded stride kills the stride-300 8-way
// bank conflicts of R8). Dot = 19 float4 pairs. Quarter combine shfl_xor(1,2),
// gate butterfly shfl_xor(4,8).
// Poll is DOUBLE-PUMPED: two in-flight tag-load sets halve the detect period.
// h exchanged via tagged u64 hbuf[dir][slot][dim] at AGENT scope (tag=step);
// 2 rotating slots race-free: every wave is producer AND consumer.
__global__ __launch_bounds__(512, 1) void scan_kernel(
    const float* __restrict__ Whh_f, const float* __restrict__ Whh_b,
    const int* __restrict__ meta, const int* __restrict__ map,
    unsigned long long* __restrict__ hbuf, const float* __restrict__ xw,
    float* __restrict__ padded) {
    const int N = meta[0];
    const int b = blockIdx.x;
    const int dir = b / 10;
    const int blk = b % 10;
    const int tid = threadIdx.x;
    const int wave = tid >> 6;
    const int lane = tid & 63;
    const int q    = lane & 3;
    const int gate = (lane >> 2) & 3;
    const int dloc = lane >> 4;
    const int ld_raw = wave * 4 + dloc;
    const bool vd = (ld_raw < 30);
    const int ld = vd ? ld_raw : 29;      // clamp invalid tail lanes
    const int lr = gate * 30 + ld;        // local weight row 0..119
    const int d  = blk * 30 + ld;         // h dim
    const int row = gate * H_ + d;        // xw row

    __shared__ float w_lds[120 * WSTRIDE];   // 146,400 B
    __shared__ float hl[8][304];             //   9,728 B (total 156,128 B)

    const float* Whh = dir ? Whh_b : Whh_f;
    // ---- stage weight slice into LDS (once) ----
    for (int i = tid; i < 120 * 75; i += 512) {
        const int r2 = i / 75;
        const int c4 = (i % 75) * 4;
        const int g2 = r2 / 30, l2 = r2 % 30;
        const int grow = g2 * H_ + blk * 30 + l2;
        *(float4*)(&w_lds[r2 * WSTRIDE + c4]) = *(const float4*)(Whh + (size_t)grow * H_ + c4);
    }
    // zero pad cols 300..304 of each row
    for (int i = tid; i < 120 * 5; i += 512)
        w_lds[(i / 5) * WSTRIDE + 300 + (i % 5)] = 0.f;
    if (lane < 4) hl[wave][300 + lane] = 0.f;
    __syncthreads();

    const float* wrow = &w_lds[lr * WSTRIDE + q * 76];
    const float* xwd = xw + (size_t)dir * XW_STRIDE;
    unsigned long long* hb = hbuf + dir * 2 * 320;
    float* hw = hl[wave];

    float c = 0.f;
    const bool storer = (vd && gate == 0 && q == 0);
    const int pd = dir * H_ + d;

    int n_cur = dir ? (N - 1) : 0;
    float xw_cur = xwd[(size_t)n_cur * R_ + row];
    int   m_cur  = map[n_cur];

    for (int t = 0; t < N; t++) {
        // ---- poll h_t (tag == t), double-pumped ----
        const unsigned long long* hp = hb + (size_t)(t & 1) * 320;
        const unsigned int want = (unsigned int)t;
        const unsigned long long wanthi = (unsigned long long)want << 32;
        unsigned long long a0,a1,a2,a3,a4, b0,b1,b2,b3,b4, d0,d1,d2,d3,d4;
        #define PLOAD(x0,x1,x2,x3,x4) \
            x0 = __hip_atomic_load(hp + lane,       __ATOMIC_RELAXED, __HIP_MEMORY_SCOPE_AGENT); \
            x1 = __hip_atomic_load(hp + 64  + lane, __ATOMIC_RELAXED, __HIP_MEMORY_SCOPE_AGENT); \
            x2 = __hip_atomic_load(hp + 128 + lane, __ATOMIC_RELAXED, __HIP_MEMORY_SCOPE_AGENT); \
            x3 = __hip_atomic_load(hp + 192 + lane, __ATOMIC_RELAXED, __HIP_MEMORY_SCOPE_AGENT); \
            x4 = (lane < 44) ? __hip_atomic_load(hp + 256 + lane, __ATOMIC_RELAXED, __HIP_MEMORY_SCOPE_AGENT) : wanthi;
        #define POK(x0,x1,x2,x3,x4) \
            (((unsigned int)(x0 >> 32) == want) && ((unsigned int)(x1 >> 32) == want) && \
             ((unsigned int)(x2 >> 32) == want) && ((unsigned int)(x3 >> 32) == want) && \
             ((unsigned int)(x4 >> 32) == want))
        PLOAD(a0,a1,a2,a3,a4)
        for (;;) {
            PLOAD(b0,b1,b2,b3,b4)
            if (POK(a0,a1,a2,a3,a4)) { d0=a0; d1=a1; d2=a2; d3=a3; d4=a4; break; }
            PLOAD(a0,a1,a2,a3,a4)
            if (POK(b0,b1,b2,b3,b4)) { d0=b0; d1=b1; d2=b2; d3=b3; d4=b4; break; }
        }
        #undef PLOAD
        #undef POK

        // stage h into this wave's LDS copy
        hw[lane]        = __uint_as_float((unsigned int)d0);
        hw[64  + lane]  = __uint_as_float((unsigned int)d1);
        hw[128 + lane]  = __uint_as_float((unsigned int)d2);
        hw[192 + lane]  = __uint_as_float((unsigned int)d3);
        if (lane < 44) hw[256 + lane] = __uint_as_float((unsigned int)d4);

        // prefetch next step's xw/map (latency hides under dot+publish)
        float xw_nxt = xw_cur; int m_nxt = m_cur;
        if (t + 1 < N) {
            const int nn = dir ? (N - 2 - t) : (t + 1);
            xw_nxt = xwd[(size_t)nn * R_ + row];
            m_nxt  = map[nn];
        }

        // ---- quarter-dot: 19 float4 pairs from padded LDS ----
        const float* hbase = hw + q * 76;
        float a0f = 0.f, a1f = 0.f, a2f = 0.f, a3f = 0.f;
        #pragma unroll
        for (int j = 0; j < 19; j++) {
            const float4 wj = *(const float4*)(wrow + 4*j);
            const float4 h4 = *(const float4*)(hbase + 4*j);
            a0f = fmaf(wj.x, h4.x, a0f);
            a1f = fmaf(wj.y, h4.y, a1f);
            a2f = fmaf(wj.z, h4.z, a2f);
            a3f = fmaf(wj.w, h4.w, a3f);
        }
        float sum = (a0f + a1f) + (a2f + a3f);
        sum += __shfl_xor(sum, 1);     // combine quarters (lane bits 0..1)
        sum += __shfl_xor(sum, 2);
        const float acc = xw_cur + sum;

        // ---- gate butterfly over lane bits 2..3 ----
        const float aa = acc;
        const float bb = __shfl_xor(acc, 4);
        const float cc = __shfl_xor(acc, 8);
        const float dd = __shfl_xor(bb, 8);
        const float vi = sel4(gate,     aa, bb, cc, dd);
        const float vf = sel4(gate ^ 1, aa, bb, cc, dd);
        const float vg = sel4(gate ^ 2, aa, bb, cc, dd);
        const float vo = sel4(gate ^ 3, aa, bb, cc, dd);

        c = sigm(vf) * c + sigm(vi) * tanh_fast(vg);
        const float h = sigm(vo) * tanh_fast(c);

        // ---- publish h_{t+1}; padded store rides behind it ----
        if (storer) {
            const unsigned long long pv =
                ((unsigned long long)(unsigned int)(t + 1) << 32) |
                (unsigned long long)__float_as_uint(h);
            __hip_atomic_store(hb + (size_t)((t + 1) & 1) * 320 + d, pv,
                               __ATOMIC_RELAXED, __HIP_MEMORY_SCOPE_AGENT);
            padded[(size_t)m_cur * D_ + pd] = h;
        }
        xw_cur = xw_nxt;
        m_cur  = m_nxt;
    }
}

// ---------------- per-sentence attention + maxpool ---------------------------
__global__ __launch_bounds__(256) void attn_kernel(
    const int* __restrict__ lengths, const float* __restrict__ padded,
    float* __restrict__ out) {
    const int s = blockIdx.x;
    const int tid = threadIdx.x;
    const int Ls = lengths[s];
    const float* P = padded + (size_t)s * L_ * D_;
    __shared__ float sc[16][128];
    const float scale = 0.040824829046386304f;  // 1/sqrt(600)
    float vmax0 = -1e30f, vmax1 = -1e30f, vmax2 = -1e30f;

    const int nqt = (Ls + 15) / 16;
    for (int qt = 0; qt < nqt; qt++) {
        const int q0 = qt * 16;
        if (tid < 128) {
            float acc[16];
            #pragma unroll
            for (int i = 0; i < 16; i++) acc[i] = -1e30f;
            if (tid < Ls) {
                #pragma unroll
                for (int i = 0; i < 16; i++) acc[i] = 0.f;
                const float* pk = P + (size_t)tid * D_;
                for (int e4 = 0; e4 < 150; e4++) {
                    const float4 k4 = *(const float4*)(pk + 4*e4);
                    #pragma unroll
                    for (int i = 0; i < 16; i++) {
                        const float4 q4 = *(const float4*)(P + (size_t)(q0 + i) * D_ + 4*e4);
                        acc[i] = fmaf(k4.x, q4.x, acc[i]);
                        acc[i] = fmaf(k4.y, q4.y, acc[i]);
                        acc[i] = fmaf(k4.z, q4.z, acc[i]);
                        acc[i] = fmaf(k4.w, q4.w, acc[i]);
                    }
                }
                #pragma unroll
                for (int i = 0; i < 16; i++) acc[i] *= scale;
            }
            #pragma unroll
            for (int i = 0; i < 16; i++) sc[i][tid] = acc[i];
        }
        __syncthreads();

        {
            const int w = tid >> 6, l = tid & 63;
            #pragma unroll
            for (int ii = 0; ii < 4; ii++) {
                const int i = w * 4 + ii;
                float x0 = sc[i][l], x1 = sc[i][64 + l];
                float mx = fmaxf(x0, x1);
                #pragma unroll
                for (int off = 32; off; off >>= 1) mx = fmaxf(mx, __shfl_xor(mx, off));
                float e0 = expf(x0 - mx), e1 = expf(x1 - mx);
                float sm = e0 + e1;
                #pragma unroll
                for (int off = 32; off; off >>= 1) sm += __shfl_xor(sm, off);
                const float inv = 1.f / sm;
                sc[i][l] = e0 * inv;
                sc[i][64 + l] = e1 * inv;
            }
        }
        __syncthreads();

        #pragma unroll
        for (int j = 0; j < 3; j++) {
            const int dd = j * 256 + tid;
            if (dd < D_) {
                float ca[16];
                #pragma unroll
                for (int i = 0; i < 16; i++) ca[i] = 0.f;
                for (int k4 = 0; k4 < 32; k4++) {
                    const float p0 = P[(size_t)(4*k4 + 0) * D_ + dd];
                    const float p1 = P[(size_t)(4*k4 + 1) * D_ + dd];
                    const float p2 = P[(size_t)(4*k4 + 2) * D_ + dd];
                    const float p3 = P[(size_t)(4*k4 + 3) * D_ + dd];
                    #pragma unroll
                    for (int i = 0; i < 16; i++) {
                        const float4 pr = *(const float4*)(&sc[i][4*k4]);
                        ca[i] = fmaf(pr.x, p0, ca[i]);
                        ca[i] = fmaf(pr.y, p1, ca[i]);
                        ca[i] = fmaf(pr.z, p2, ca[i]);
                        ca[i] = fmaf(pr.w, p3, ca[i]);
                    }
                }
                float vm = (j == 0) ? vmax0 : (j == 1) ? vmax1 : vmax2;
                #pragma unroll
                for (int i = 0; i < 16; i++)
                    if (q0 + i < Ls) vm = fmaxf(vm, ca[i]);
                if (j == 0) vmax0 = vm; else if (j == 1) vmax1 = vm; else vmax2 = vm;
            }
        }
        __syncthreads();
    }
    if (tid < D_)        out[(size_t)s * D_ + tid] = vmax0;
    if (256 + tid < D_)  out[(size_t)s * D_ + 256 + tid] = vmax1;
    if (512 + tid < D_)  out[(size_t)s * D_ + 512 + tid] = vmax2;
}

// ---------------- launcher ----------------------------------------------------
extern "C" void kernel_launch(void* const* d_in, const int* in_sizes, int n_in,
                              void* d_out, int out_size, void* d_ws, size_t ws_size,
                              hipStream_t stream) {
    const int*   tokens  = (const int*)d_in[0];
    const int*   lengths = (const int*)d_in[1];
    const float* table   = (const float*)d_in[2];
    const float* Wih_f   = (const float*)d_in[3];
    const float* Whh_f   = (const float*)d_in[4];
    const float* bih_f   = (const float*)d_in[5];
    const float* bhh_f   = (const float*)d_in[6];
    const float* Wih_b   = (const float*)d_in[7];
    const float* Whh_b   = (const float*)d_in[8];
    const float* bih_b   = (const float*)d_in[9];
    const float* bhh_b   = (const float*)d_in[10];
    float* out = (float*)d_out;

    char* ws = (char*)d_ws;
    int* meta                 = (int*)(ws + 0);                       // 256 B
    int* map                  = (int*)(ws + 256);                     // 64 KB
    unsigned long long* hbuf  = (unsigned long long*)(ws + 256 + 65536);        // 10240 B
    float* xw                 = (float*)(ws + 256 + 65536 + 10240);   // 2*16384*1200 f32
    float* padded             = (float*)(ws + 256 + 65536 + 10240 + (size_t)2*NMAX*R_*4);

    prep_kernel<<<1, 256, 0, stream>>>(lengths, meta, map, hbuf);
    xw_kernel<<<dim3(NMAX/32, 40), 256, 0, stream>>>(tokens, table,
        Wih_f, bih_f, bhh_f, Wih_b, bih_b, bhh_b, meta, map, xw);
    scan_kernel<<<20, 512, 0, stream>>>(Whh_f, Whh_b, meta, map, hbuf, xw, padded);
    attn_kernel<<<S_, 256, 0, stream>>>(lengths, padded, out);
}

// Round 10
// 46735.419 us; speedup vs baseline: 1.3229x; 1.3229x over previous
//
#include <hip/hip_runtime.h>
#include <stdint.h>

#define S_ 128
#define L_ 128
#define E_ 300
#define H_ 300
#define NMAX (S_*L_)          // 16384
#define R_ 1200               // 4*H
#define D_ 600
#define XW_STRIDE ((size_t)NMAX*R_)

// ---------------- prep: prefix sums, token->(s,l) map, zero h buffers -------
__global__ void prep_kernel(const int* __restrict__ lengths, int* __restrict__ meta,
                            int* __restrict__ map, unsigned long long* __restrict__ hbuf) {
    __shared__ int offs[S_];
    int tid = threadIdx.x;
    if (tid == 0) {
        int acc = 0;
        for (int s = 0; s < S_; s++) { offs[s] = acc; acc += lengths[s]; }
        meta[0] = acc;   // N total
    }
    __syncthreads();
    for (int s = tid; s < S_; s += blockDim.x) {
        int o = offs[s], len = lengths[s];
        for (int l = 0; l < len; l++) map[o + l] = s * L_ + l;
    }
    // zero hbuf: [2 dirs][2 slots][320] u64 (tag 0 == valid h_0 = 0)
    for (int i = tid; i < 2*2*320; i += blockDim.x) hbuf[i] = 0ull;
}

// ---------------- xw = embeds @ Wih^T + (bih+bhh), both directions ----------
// Quarter-split: unit u = by*256+tid; r = u>>2 (output row 0..2559), q = u&3.
// 19 float4 weights/thread (no-spill footprint); shfl_xor(1,2) combine.
__global__ __launch_bounds__(256, 1) void xw_kernel(
    const int* __restrict__ tokens, const float* __restrict__ table,
    const float* __restrict__ Wih_f, const float* __restrict__ bih_f, const float* __restrict__ bhh_f,
    const float* __restrict__ Wih_b, const float* __restrict__ bih_b, const float* __restrict__ bhh_b,
    const int* __restrict__ meta, const int* __restrict__ map, float* __restrict__ xw) {
    const int N = meta[0];
    const int n0 = blockIdx.x * 32;
    if (n0 >= N) return;
    const int u = blockIdx.y * 256 + threadIdx.x;   // 0..10239
    const int r = u >> 2;                           // output row 0..2559
    const int q = u & 3;                            // column quarter
    const bool vr = (r < 2*R_);
    const int dir = (r >= R_) ? 1 : 0;
    const int rr = vr ? (r - dir * R_) : 0;
    const float* W = dir ? Wih_b : Wih_f;
    float bias = 0.f;
    float4 w4[19];
    {
        const float* wr = W + (size_t)rr * E_ + q * 76;
        #pragma unroll
        for (int j = 0; j < 18; j++) w4[j] = vr ? *(const float4*)(wr + 4*j)
                                                : make_float4(0.f,0.f,0.f,0.f);
        w4[18] = (vr && q < 3) ? *(const float4*)(wr + 72) : make_float4(0.f,0.f,0.f,0.f);
        if (vr && q == 0) bias = dir ? (bih_b[rr] + bhh_b[rr]) : (bih_f[rr] + bhh_f[rr]);
    }
    // q==3's 19th chunk stays in-bounds (reload offset 0; weight is zero there)
    const int off18 = (q < 3) ? 72 : 0;
    float* xwd = xw + (size_t)dir * XW_STRIDE;
    const int iend = min(32, N - n0);
    for (int i = 0; i < iend; i++) {
        const int n = n0 + i;
        const int tok = tokens[map[n]];                  // uniform
        const float* arow = table + (size_t)tok * E_ + q * 76;
        float a0 = bias, a1 = 0.f, a2 = 0.f, a3 = 0.f;
        #pragma unroll
        for (int j = 0; j < 18; j++) {
            float4 a4 = *(const float4*)(arow + 4*j);    // 4 addrs/wave
            a0 = fmaf(w4[j].x, a4.x, a0);
            a1 = fmaf(w4[j].y, a4.y, a1);
            a2 = fmaf(w4[j].z, a4.z, a2);
            a3 = fmaf(w4[j].w, a4.w, a3);
        }
        {
            float4 a4 = *(const float4*)(arow + off18);
            a0 = fmaf(w4[18].x, a4.x, a0);
            a1 = fmaf(w4[18].y, a4.y, a1);
            a2 = fmaf(w4[18].z, a4.z, a2);
            a3 = fmaf(w4[18].w, a4.w, a3);
        }
        float sum = (a0 + a1) + (a2 + a3);
        sum += __shfl_xor(sum, 1);
        sum += __shfl_xor(sum, 2);
        if (vr && q == 0) xwd[(size_t)n * R_ + rr] = sum;
    }
}

// ---------------- sequential BiLSTM scan -------------------------------------
__device__ __forceinline__ float sel4(int m, float a, float b, float c, float d) {
    float r = a;
    r = (m == 1) ? b : r;
    r = (m == 2) ? c : r;
    r = (m == 3) ? d : r;
    return r;
}
// fast activations (v_exp_f32 + v_rcp_f32); NaN-free at +/-inf
__device__ __forceinline__ float sigm(float x) {
    return __builtin_amdgcn_rcpf(1.f + __expf(-x));
}
__device__ __forceinline__ float tanh_fast(float x) {
    return 1.f - 2.f * __builtin_amdgcn_rcpf(1.f + __expf(2.f * x));
}

#define WSTRIDE 305   // 305 mod 32 = 17 (odd): 32 consecutive rows hit all banks

// grid: 20 blocks x 256 threads (R8's proven sync shape). block b: dir=b/10,
// blk=b%10 (30 h-dims). thread: pair=tid>>1 owns LDS row pair (gate=pair&3,
// d=30*blk+(pair>>2)); half=tid&1 owns 152 cols (cbase=half*152; half1's last
// float4 reads zeroed pad cols 300..303 -> uniform 38-f4 dot, no branch).
// Weights in LDS, PADDED stride 305: row r starts at bank 17r mod 32; a wave's
// 32 distinct rows cover all banks; 2 lanes/bank = conflict-free (m136).
// Poll single-pump (R8 proven; R9's double-pump = vmcnt(0) serialization +
// 2x traffic = collapse). xw/map for t+1 prefetched AFTER detect (hides under
// dot, off the poll's waitcnt path).
// h exchanged via tagged u64 hbuf[dir][slot][dim] at AGENT scope (tag=step);
// 2 rotating slots race-free: every wave is producer AND consumer.
__global__ __launch_bounds__(256, 1) void scan_kernel(
    const float* __restrict__ Whh_f, const float* __restrict__ Whh_b,
    const int* __restrict__ meta, const int* __restrict__ map,
    unsigned long long* __restrict__ hbuf, const float* __restrict__ xw,
    float* __restrict__ padded) {
    const int N = meta[0];
    const int b = blockIdx.x;
    const int dir = b / 10;
    const int blk = b % 10;
    const int tid = threadIdx.x;
    const int wave = tid >> 6;
    const int lane = tid & 63;
    const int pair = tid >> 1;            // 0..127 (rows 120..127 invalid)
    const int half = tid & 1;
    const int gate = pair & 3;
    const int d = 30 * blk + (pair >> 2); // h dim this row-group computes
    const bool vd = (pair < 120);         // 30 dims x 4 gates

    __shared__ float w_lds[120 * WSTRIDE];   // 146,400 B
    __shared__ float hl[4][304];             //   4,864 B (total 151,264 B)

    const float* Whh = dir ? Whh_b : Whh_f;
    // ---- stage weight slice into LDS (once) ----
    for (int i = tid; i < 120 * 75; i += 256) {
        const int r2 = i / 75;            // local row (pair index semantics)
        const int c4 = (i % 75) * 4;
        const int grow = (r2 & 3) * H_ + blk * 30 + (r2 >> 2);
        *(float4*)(&w_lds[r2 * WSTRIDE + c4]) = *(const float4*)(Whh + (size_t)grow * H_ + c4);
    }
    // zero pad cols 300..304 of each row
    for (int i = tid; i < 120 * 5; i += 256)
        w_lds[(i / 5) * WSTRIDE + 300 + (i % 5)] = 0.f;
    if (lane < 4) hl[wave][300 + lane] = 0.f;   // h pad cols 300..303
    __syncthreads();

    const int row = gate * H_ + (vd ? d : 0);      // xw row for this pair
    const int cbase = half * 152;                  // 152-col halves (+pad)
    const float* wrow = &w_lds[(vd ? pair : 0) * WSTRIDE + cbase];

    const float* xwd = xw + (size_t)dir * XW_STRIDE;
    unsigned long long* hb = hbuf + dir * 2 * 320;
    float* hw = hl[wave];

    float c = 0.f;
    const bool storer = (vd && gate == 0 && half == 0);
    const int pd = dir * H_ + d;

    int n_cur = dir ? (N - 1) : 0;
    float xw_cur = xwd[(size_t)n_cur * R_ + row];
    int   m_cur  = map[n_cur];

    for (int t = 0; t < N; t++) {
        // ---- poll h_t (tag == t), single-pump (R8 proven) ----
        const unsigned long long* hp = hb + (size_t)(t & 1) * 320;
        const unsigned int want = (unsigned int)t;
        unsigned long long v0, v1, v2, v3, v4;
        for (;;) {
            v0 = __hip_atomic_load(hp + lane,        __ATOMIC_RELAXED, __HIP_MEMORY_SCOPE_AGENT);
            v1 = __hip_atomic_load(hp + 64  + lane,  __ATOMIC_RELAXED, __HIP_MEMORY_SCOPE_AGENT);
            v2 = __hip_atomic_load(hp + 128 + lane,  __ATOMIC_RELAXED, __HIP_MEMORY_SCOPE_AGENT);
            v3 = __hip_atomic_load(hp + 192 + lane,  __ATOMIC_RELAXED, __HIP_MEMORY_SCOPE_AGENT);
            v4 = (lane < 44) ? __hip_atomic_load(hp + 256 + lane, __ATOMIC_RELAXED, __HIP_MEMORY_SCOPE_AGENT)
                             : ((unsigned long long)want << 32);
            bool ok = ((unsigned int)(v0 >> 32) == want) &&
                      ((unsigned int)(v1 >> 32) == want) &&
                      ((unsigned int)(v2 >> 32) == want) &&
                      ((unsigned int)(v3 >> 32) == want) &&
                      ((unsigned int)(v4 >> 32) == want);
            if (ok) break;
        }
        // stage h into this wave's LDS copy
        hw[lane]        = __uint_as_float((unsigned int)v0);
        hw[64  + lane]  = __uint_as_float((unsigned int)v1);
        hw[128 + lane]  = __uint_as_float((unsigned int)v2);
        hw[192 + lane]  = __uint_as_float((unsigned int)v3);
        if (lane < 44) hw[256 + lane] = __uint_as_float((unsigned int)v4);

        // prefetch next step's xw/map (hides under the dot, off the poll path)
        float xw_nxt = xw_cur; int m_nxt = m_cur;
        if (t + 1 < N) {
            const int nn = dir ? (N - 2 - t) : (t + 1);
            xw_nxt = xwd[(size_t)nn * R_ + row];
            m_nxt  = map[nn];
        }

        // ---- half-dot: uniform 38 float4 pairs from padded LDS ----
        const float* hbase = hw + cbase;
        float a0 = 0.f, a1 = 0.f, a2 = 0.f, a3 = 0.f;
        #pragma unroll
        for (int j = 0; j < 38; j++) {
            const float4 wj = *(const float4*)(wrow + 4*j);
            const float4 h4 = *(const float4*)(hbase + 4*j);
            a0 = fmaf(wj.x, h4.x, a0);
            a1 = fmaf(wj.y, h4.y, a1);
            a2 = fmaf(wj.z, h4.z, a2);
            a3 = fmaf(wj.w, h4.w, a3);
        }
        float sum = (a0 + a1) + (a2 + a3);
        sum += __shfl_xor(sum, 1);                 // combine halves
        const float acc = xw_cur + sum;

        // ---- gate butterfly over tid bits 1..2 ----
        const float aa = acc;
        const float bb = __shfl_xor(acc, 2);
        const float cc = __shfl_xor(acc, 4);
        const float dd = __shfl_xor(bb, 4);
        const float vi = sel4(gate,     aa, bb, cc, dd);
        const float vf = sel4(gate ^ 1, aa, bb, cc, dd);
        const float vg = sel4(gate ^ 2, aa, bb, cc, dd);
        const float vo = sel4(gate ^ 3, aa, bb, cc, dd);

        c = sigm(vf) * c + sigm(vi) * tanh_fast(vg);
        const float h = sigm(vo) * tanh_fast(c);

        // ---- publish h_{t+1}; padded store rides behind it ----
        if (storer) {
            const unsigned long long pv =
                ((unsigned long long)(unsigned int)(t + 1) << 32) |
                (unsigned long long)__float_as_uint(h);
            __hip_atomic_store(hb + (size_t)((t + 1) & 1) * 320 + d, pv,
                               __ATOMIC_RELAXED, __HIP_MEMORY_SCOPE_AGENT);
            padded[(size_t)m_cur * D_ + pd] = h;
        }
        xw_cur = xw_nxt;
        m_cur  = m_nxt;
    }
}

// ---------------- per-sentence attention + maxpool ---------------------------
__global__ __launch_bounds__(256) void attn_kernel(
    const int* __restrict__ lengths, const float* __restrict__ padded,
    float* __restrict__ out) {
    const int s = blockIdx.x;
    const int tid = threadIdx.x;
    const int Ls = lengths[s];
    const float* P = padded + (size_t)s * L_ * D_;
    __shared__ float sc[16][128];
    const float scale = 0.040824829046386304f;  // 1/sqrt(600)
    float vmax0 = -1e30f, vmax1 = -1e30f, vmax2 = -1e30f;

    const int nqt = (Ls + 15) / 16;
    for (int qt = 0; qt < nqt; qt++) {
        const int q0 = qt * 16;
        if (tid < 128) {
            float acc[16];
            #pragma unroll
            for (int i = 0; i < 16; i++) acc[i] = -1e30f;
            if (tid < Ls) {
                #pragma unroll
                for (int i = 0; i < 16; i++) acc[i] = 0.f;
                const float* pk = P + (size_t)tid * D_;
                for (int e4 = 0; e4 < 150; e4++) {
                    const float4 k4 = *(const float4*)(pk + 4*e4);
                    #pragma unroll
                    for (int i = 0; i < 16; i++) {
                        const float4 q4 = *(const float4*)(P + (size_t)(q0 + i) * D_ + 4*e4);
                        acc[i] = fmaf(k4.x, q4.x, acc[i]);
                        acc[i] = fmaf(k4.y, q4.y, acc[i]);
                        acc[i] = fmaf(k4.z, q4.z, acc[i]);
                        acc[i] = fmaf(k4.w, q4.w, acc[i]);
                    }
                }
                #pragma unroll
                for (int i = 0; i < 16; i++) acc[i] *= scale;
            }
            #pragma unroll
            for (int i = 0; i < 16; i++) sc[i][tid] = acc[i];
        }
        __syncthreads();

        {
            const int w = tid >> 6, l = tid & 63;
            #pragma unroll
            for (int ii = 0; ii < 4; ii++) {
                const int i = w * 4 + ii;
                float x0 = sc[i][l], x1 = sc[i][64 + l];
                float mx = fmaxf(x0, x1);
                #pragma unroll
                for (int off = 32; off; off >>= 1) mx = fmaxf(mx, __shfl_xor(mx, off));
                float e0 = expf(x0 - mx), e1 = expf(x1 - mx);
                float sm = e0 + e1;
                #pragma unroll
                for (int off = 32; off; off >>= 1) sm += __shfl_xor(sm, off);
                const float inv = 1.f / sm;
                sc[i][l] = e0 * inv;
                sc[i][64 + l] = e1 * inv;
            }
        }
        __syncthreads();

        #pragma unroll
        for (int j = 0; j < 3; j++) {
            const int dd = j * 256 + tid;
            if (dd < D_) {
                float ca[16];
                #pragma unroll
                for (int i = 0; i < 16; i++) ca[i] = 0.f;
                for (int k4 = 0; k4 < 32; k4++) {
                    const float p0 = P[(size_t)(4*k4 + 0) * D_ + dd];
                    const float p1 = P[(size_t)(4*k4 + 1) * D_ + dd];
                    const float p2 = P[(size_t)(4*k4 + 2) * D_ + dd];
                    const float p3 = P[(size_t)(4*k4 + 3) * D_ + dd];
                    #pragma unroll
                    for (int i = 0; i < 16; i++) {
                        const float4 pr = *(const float4*)(&sc[i][4*k4]);
                        ca[i] = fmaf(pr.x, p0, ca[i]);
                        ca[i] = fmaf(pr.y, p1, ca[i]);
                        ca[i] = fmaf(pr.z, p2, ca[i]);
                        ca[i] = fmaf(pr.w, p3, ca[i]);
                    }
                }
                float vm = (j == 0) ? vmax0 : (j == 1) ? vmax1 : vmax2;
                #pragma unroll
                for (int i = 0; i < 16; i++)
                    if (q0 + i < Ls) vm = fmaxf(vm, ca[i]);
                if (j == 0) vmax0 = vm; else if (j == 1) vmax1 = vm; else vmax2 = vm;
            }
        }
        __syncthreads();
    }
    if (tid < D_)        out[(size_t)s * D_ + tid] = vmax0;
    if (256 + tid < D_)  out[(size_t)s * D_ + 256 + tid] = vmax1;
    if (512 + tid < D_)  out[(size_t)s * D_ + 512 + tid] = vmax2;
}

// ---------------- launcher ----------------------------------------------------
extern "C" void kernel_launch(void* const* d_in, const int* in_sizes, int n_in,
                              void* d_out, int out_size, void* d_ws, size_t ws_size,
                              hipStream_t stream) {
    const int*   tokens  = (const int*)d_in[0];
    const int*   lengths = (const int*)d_in[1];
    const float* table   = (const float*)d_in[2];
    const float* Wih_f   = (const float*)d_in[3];
    const float* Whh_f   = (const float*)d_in[4];
    const float* bih_f   = (const float*)d_in[5];
    const float* bhh_f   = (const float*)d_in[6];
    const float* Wih_b   = (const float*)d_in[7];
    const float* Whh_b   = (const float*)d_in[8];
    const float* bih_b   = (const float*)d_in[9];
    const float* bhh_b   = (const float*)d_in[10];
    float* out = (float*)d_out;

    char* ws = (char*)d_ws;
    int* meta                 = (int*)(ws + 0);                       // 256 B
    int* map                  = (int*)(ws + 256);                     // 64 KB
    unsigned long long* hbuf  = (unsigned long long*)(ws + 256 + 65536);        // 10240 B
    float* xw                 = (float*)(ws + 256 + 65536 + 10240);   // 2*16384*1200 f32
    float* padded             = (float*)(ws + 256 + 65536 + 10240 + (size_t)2*NMAX*R_*4);

    prep_kernel<<<1, 256, 0, stream>>>(lengths, meta, map, hbuf);
    xw_kernel<<<dim3(NMAX/32, 40), 256, 0, stream>>>(tokens, table,
        Wih_f, bih_f, bhh_f, Wih_b, bih_b, bhh_b, meta, map, xw);
    scan_kernel<<<20, 256, 0, stream>>>(Whh_f, Whh_b, meta, map, hbuf, xw, padded);
    attn_kernel<<<S_, 256, 0, stream>>>(lengths, padded, out);
}